// Round 8
// baseline (282.194 us; speedup 1.0000x reference)
//
#include <hip/hip_runtime.h>
#include <hip/hip_bf16.h>

#define BATCH 2
#define SEQ   2048
#define EMBED 1024
#define HEADS 16
#define HDIM  64
#define NBH   (BATCH*HEADS)

typedef __attribute__((ext_vector_type(8))) short short8;
typedef __attribute__((ext_vector_type(4))) float floatx4;
typedef unsigned short u16;
typedef unsigned int   u32;

#define LOG2E 1.4426950408889634f

// async global->LDS, 16B per lane. LDS dest must be wave-uniform base + lane*16.
__device__ __forceinline__ void async_cp16(const void* g, void* l) {
  __builtin_amdgcn_global_load_lds((const __attribute__((address_space(1))) void*)g,
                                   (__attribute__((address_space(3))) void*)l,
                                   16, 0, 0);
}

__device__ __forceinline__ u32 pk2(float a, float b) {  // packed bf16x2 (RNE)
  __hip_bfloat162 t = __float22bfloat162_rn(make_float2(a, b));
  return *reinterpret_cast<u32*>(&t);
}
// convert 8 f32 (two float4) -> 8 bf16, one ds_write_b128
__device__ __forceinline__ void cvt8(const float4& a, const float4& b, void* lds) {
  uint4 o;
  o.x = pk2(a.x, a.y); o.y = pk2(a.z, a.w);
  o.z = pk2(b.x, b.y); o.w = pk2(b.z, b.w);
  *(uint4*)lds = o;
}
__device__ __forceinline__ float fexp2(float x) {  // 2^x, single v_exp_f32
#if __has_builtin(__builtin_amdgcn_exp2f)
  return __builtin_amdgcn_exp2f(x);
#else
  return __expf(x * 0.6931471805599453f);
#endif
}

// ---------------------------------------------------------------------------
// Fused QKV GEMM v5: cvt_all eliminated — f32 X,W converted during staging
// (reg-staged float4 loads -> pk2 -> ds_write_b128; T14 issue-early/
// write-late: loads for t+1 issue BEFORE compute(t), converts+writes land
// AFTER, so HBM/L2 latency hides under the MFMA phase). Structure otherwise
// = R5/R6 best (128^2, BK=32, 2-buf, 3 blocks/CU, grid 768 packs exactly,
// XCD-chunked swizzle: 4 m-panels/XCD -> X slice 2MB f32 L2-resident).
// Conversion is RNE, deterministic -> bit-identical to the old cvt pass.
// n-blocks 0..15 (Q/K): swapped operands -> [bh][s][d] packed stores.
// n-blocks 16..23 (V):  normal operands  -> V^T [bh][d][s] packed stores.
// ---------------------------------------------------------------------------
__global__ __launch_bounds__(256, 3)
void qkv_gemm(const float* __restrict__ X, const float* __restrict__ W,
              u16* __restrict__ q_ws, u16* __restrict__ k_ws,
              u16* __restrict__ vT_ws) {
  __shared__ u16 As[2][4][128][8];   // 8 KB per buf: [buf][k-chunk][row][8]
  __shared__ u16 Bs[2][4][128][8];
  const int tid  = threadIdx.x;
  const int lane = tid & 63, wv = tid >> 6;
  const int l15  = lane & 15, quad = lane >> 4;
  const int wm = (wv >> 1) << 6, wn = (wv & 1) << 6;

  // XCD-chunked bijective swizzle: 768 blocks = 8 XCDs x 96 (4 m x 24 n)
  const int orig = blockIdx.y * 24 + blockIdx.x;
  const int swz  = (orig & 7) * 96 + (orig >> 3);
  const int m0 = (swz / 24) << 7, n0 = (swz % 24) << 7;
  const bool vpath = (n0 >= 2048);

  // staging slots: 512 per array of 8 bf16; 2 per thread
  const int kb0 = tid >> 7, r0 = tid & 127;        // {0,1}
  const int kb1 = kb0 + 2, r1 = r0;                // {2,3}

  floatx4 acc[4][4];
#pragma unroll
  for (int i = 0; i < 4; ++i)
#pragma unroll
    for (int j = 0; j < 4; ++j) acc[i][j] = {0.f, 0.f, 0.f, 0.f};

  float4 xa0, xa1, xa2, xa3, wb0, wb1, wb2, wb3;

#define QKV_LOAD(kt)                                                           \
  do {                                                                         \
    const float* xp0 = X + (size_t)(m0 + r0) * EMBED + ((kt) << 5) + kb0 * 8;  \
    const float* xp1 = X + (size_t)(m0 + r1) * EMBED + ((kt) << 5) + kb1 * 8;  \
    const float* wp0 = W + (size_t)(n0 + r0) * EMBED + ((kt) << 5) + kb0 * 8;  \
    const float* wp1 = W + (size_t)(n0 + r1) * EMBED + ((kt) << 5) + kb1 * 8;  \
    xa0 = *(const float4*)xp0; xa1 = *(const float4*)(xp0 + 4);                \
    xa2 = *(const float4*)xp1; xa3 = *(const float4*)(xp1 + 4);                \
    wb0 = *(const float4*)wp0; wb1 = *(const float4*)(wp0 + 4);                \
    wb2 = *(const float4*)wp1; wb3 = *(const float4*)(wp1 + 4);                \
  } while (0)

#define QKV_WRITE(buf)                                                         \
  do {                                                                         \
    cvt8(xa0, xa1, &As[buf][kb0][r0][0]);                                      \
    cvt8(xa2, xa3, &As[buf][kb1][r1][0]);                                      \
    cvt8(wb0, wb1, &Bs[buf][kb0][r0][0]);                                      \
    cvt8(wb2, wb3, &Bs[buf][kb1][r1][0]);                                      \
  } while (0)

  // prologue: tile 0 staged through regs
  QKV_LOAD(0);
  QKV_WRITE(0);
  __syncthreads();

  if (!vpath) {
    for (int t = 0; t < 32; ++t) {
      const int cur = t & 1;
      if (t < 31) QKV_LOAD(t + 1);               // issue-early (in flight under MFMA)
      short8 af[4], bf[4];
#pragma unroll
      for (int f = 0; f < 4; ++f) {
        af[f] = *(const short8*)&As[cur][quad][wm + f * 16 + l15][0];
        bf[f] = *(const short8*)&Bs[cur][quad][wn + f * 16 + l15][0];
      }
      __builtin_amdgcn_s_setprio(1);
#pragma unroll
      for (int i = 0; i < 4; ++i)
#pragma unroll
        for (int j = 0; j < 4; ++j)
          acc[i][j] = __builtin_amdgcn_mfma_f32_16x16x32_bf16(bf[j], af[i], acc[i][j], 0, 0, 0);
      __builtin_amdgcn_s_setprio(0);
      __builtin_amdgcn_sched_barrier(0);         // keep converts below MFMAs
      if (t < 31) QKV_WRITE(cur ^ 1);            // write-late (reg dep = vm wait)
      __syncthreads();
    }

    // D: row = quad*4+r -> weight col (d); col = l15 -> X row (s)
#pragma unroll
    for (int i = 0; i < 4; ++i) {
      int mg = m0 + wm + i * 16 + l15;
      int b = mg >> 11, s = mg & 2047;
#pragma unroll
      for (int j = 0; j < 4; ++j) {
        int col0 = n0 + wn + j * 16 + (quad << 2);
        int c = col0 >> 10, hd = col0 & 1023;
        int h = hd >> 6, d0 = hd & 63;
        u16* dst = c ? k_ws : q_ws;
        uint2 w;
        w.x = pk2(acc[i][j][0], acc[i][j][1]);
        w.y = pk2(acc[i][j][2], acc[i][j][3]);
        *(uint2*)(dst + (((size_t)(b * HEADS + h)) * SEQ + s) * HDIM + d0) = w;
      }
    }
  } else {
    for (int t = 0; t < 32; ++t) {
      const int cur = t & 1;
      if (t < 31) QKV_LOAD(t + 1);
      short8 af[4], bf[4];
#pragma unroll
      for (int f = 0; f < 4; ++f) {
        af[f] = *(const short8*)&As[cur][quad][wm + f * 16 + l15][0];
        bf[f] = *(const short8*)&Bs[cur][quad][wn + f * 16 + l15][0];
      }
      __builtin_amdgcn_s_setprio(1);
#pragma unroll
      for (int i = 0; i < 4; ++i)
#pragma unroll
        for (int j = 0; j < 4; ++j)
          acc[i][j] = __builtin_amdgcn_mfma_f32_16x16x32_bf16(af[i], bf[j], acc[i][j], 0, 0, 0);
      __builtin_amdgcn_s_setprio(0);
      __builtin_amdgcn_sched_barrier(0);
      if (t < 31) QKV_WRITE(cur ^ 1);
      __syncthreads();
    }

    // D: row = quad*4+r -> s (4 consecutive); col = l15 -> weight col (h,d)
#pragma unroll
    for (int i = 0; i < 4; ++i) {
      int mg0 = m0 + wm + i * 16 + (quad << 2);
      int b = mg0 >> 11, s0 = mg0 & 2047;
#pragma unroll
      for (int j = 0; j < 4; ++j) {
        int col = n0 + wn + j * 16 + l15;
        int hd = col & 1023;
        int h = hd >> 6, d = hd & 63;
        uint2 w;
        w.x = pk2(acc[i][j][0], acc[i][j][1]);
        w.y = pk2(acc[i][j][2], acc[i][j][3]);
        *(uint2*)(vT_ws + (((size_t)(b * HEADS + h)) * HDIM + d) * SEQ + s0) = w;
      }
    }
  }
#undef QKV_LOAD
#undef QKV_WRITE
}

// ---------------------------------------------------------------------------
// Flash attention v9: 32 q-rows per wave (K/V fragment amortization).
// (unchanged from R3/R5/R6 — verified, <63 µs)
// ---------------------------------------------------------------------------
__global__ __launch_bounds__(256, 2)
void attn_kernel(const u16* __restrict__ q_ws, const u16* __restrict__ k_ws,
                 const u16* __restrict__ vT_ws, const int* __restrict__ mask,
                 u16* __restrict__ ao) {
  __shared__ u16 Ks[8][64][8];     // 8 KB [d/8][t][8]
  __shared__ u16 Vt[8][64][8];     // 8 KB [t/8][d][8]
  __shared__ u16 Ps[4][32][68];    // 17 KB P^T [wave][q][t+pad4]
  __shared__ float mskf[SEQ];      // 8 KB whole-row mask shift table

  const int tid  = threadIdx.x;
  const int lane = tid & 63, wv = tid >> 6;
  const int l15  = lane & 15, quad = lane >> 4;
  const int bh = blockIdx.x;                 // x = bh -> XCD = bh%8 (L2 reuse)
  const int b  = bh >> 4, h = bh & 15;
  const int qrw = (blockIdx.y << 7) + (wv << 5);   // 32 q-rows per wave

  const u16* Qb  = q_ws  + (size_t)bh * SEQ * HDIM;
  const u16* Kb  = k_ws  + (size_t)bh * SEQ * HDIM;
  const u16* VbT = vT_ws + (size_t)bh * HDIM * SEQ;

  // per-thread staging coords (wave-uniform kb, lane-contig r)
  const int kb0 = tid >> 6, r0 = tid & 63;
  const int kb1 = (tid + 256) >> 6, r1 = tid & 63;

  // mask -> fixed-shift table, once per block
#pragma unroll
  for (int i = 0; i < 8; ++i) {
    int idx = (i << 8) + tid;
    mskf[idx] = mask[b * SEQ + idx] ? -12.0f : -1e30f;
  }

  // tile 0 -> LDS (async, linear dest)
  async_cp16(Kb + (size_t)r0 * HDIM + kb0 * 8, &Ks[kb0][r0][0]);
  async_cp16(Kb + (size_t)r1 * HDIM + kb1 * 8, &Ks[kb1][r1][0]);
  async_cp16(VbT + (size_t)r0 * SEQ + kb0 * 8, &Vt[kb0][r0][0]);
  async_cp16(VbT + (size_t)r1 * SEQ + kb1 * 8, &Vt[kb1][r1][0]);

  // Q B-frags, two q-halves: B[k=d=quad*8+j][n=q=qh*16+l15], pre-scaled 1/8
  short8 qf[2][2];
#pragma unroll
  for (int qh = 0; qh < 2; ++qh)
#pragma unroll
    for (int s = 0; s < 2; ++s) {
      short8 v = *(const short8*)(Qb + (size_t)(qrw + qh * 16 + l15) * HDIM + s * 32 + quad * 8);
#pragma unroll
      for (int e = 0; e < 8; ++e) {
        union { float f; u32 u; } x;
        x.u = ((u32)(u16)v[e]) << 16;
        x.f *= 0.125f;
        v[e] = (short)(x.u >> 16);
      }
      qf[qh][s] = v;
    }

  // tile 1 -> regs
  short8 k0r, k1r, v0r, v1r;
  k0r = *(const short8*)(Kb + (size_t)(64 + r0) * HDIM + kb0 * 8);
  k1r = *(const short8*)(Kb + (size_t)(64 + r1) * HDIM + kb1 * 8);
  v0r = *(const short8*)(VbT + (size_t)r0 * SEQ + 64 + kb0 * 8);
  v1r = *(const short8*)(VbT + (size_t)r1 * SEQ + 64 + kb1 * 8);

  float l_acc[2] = {0.f, 0.f};     // in-lane partial sums (scaled 2^-12)
  floatx4 O[4][2];
#pragma unroll
  for (int dt = 0; dt < 4; ++dt)
#pragma unroll
    for (int qh = 0; qh < 2; ++qh) O[dt][qh] = {0.f, 0.f, 0.f, 0.f};

  __syncthreads();                 // tile0 + mask table visible (one-time drain)

  for (int it = 0; it < SEQ / 64; ++it) {
    const int t0 = it << 6;

    // S^T = K·(Q/8)^T : D[t=nt*16+quad*4+r][q=qh*16+l15]; kf reused 2x
    floatx4 sc[4][2];
    __builtin_amdgcn_s_setprio(1);
#pragma unroll
    for (int nt = 0; nt < 4; ++nt) {
      sc[nt][0] = {0.f, 0.f, 0.f, 0.f};
      sc[nt][1] = {0.f, 0.f, 0.f, 0.f};
#pragma unroll
      for (int s = 0; s < 2; ++s) {
        short8 kf = *(const short8*)&Ks[s * 4 + quad][nt * 16 + l15][0];
        sc[nt][0] = __builtin_amdgcn_mfma_f32_16x16x32_bf16(kf, qf[0][s], sc[nt][0], 0, 0, 0);
        sc[nt][1] = __builtin_amdgcn_mfma_f32_16x16x32_bf16(kf, qf[1][s], sc[nt][1], 0, 0, 0);
      }
    }
    __builtin_amdgcn_s_setprio(0);

    // p = 2^(s*log2e + msk); in-lane l accumulation; packed bf16 P^T store
#pragma unroll
    for (int nt = 0; nt < 4; ++nt) {
      const float4 m4 = *(const float4*)&mskf[t0 + nt * 16 + (quad << 2)];
#pragma unroll
      for (int qh = 0; qh < 2; ++qh) {
        float pv[4];
#pragma unroll
        for (int r = 0; r < 4; ++r) {
          pv[r] = fexp2(fmaf(sc[nt][qh][r], LOG2E, (&m4.x)[r]));
          l_acc[qh] += pv[r];
        }
        uint2 w;
        w.x = pk2(pv[0], pv[1]); w.y = pk2(pv[2], pv[3]);
        *(uint2*)&Ps[wv][qh * 16 + l15][nt * 16 + (quad << 2)] = w;
      }
    }

    // O^T += V^T·P^T : A = Vt (m=d), B = Ps (n=q); vf reused 2x; wave-local
    __builtin_amdgcn_s_setprio(1);
#pragma unroll
    for (int tch = 0; tch < 2; ++tch) {
      short8 pf0 = *(const short8*)&Ps[wv][l15][tch * 32 + quad * 8];
      short8 pf1 = *(const short8*)&Ps[wv][16 + l15][tch * 32 + quad * 8];
#pragma unroll
      for (int dt = 0; dt < 4; ++dt) {
        short8 vf = *(const short8*)&Vt[tch * 4 + quad][dt * 16 + l15][0];
        O[dt][0] = __builtin_amdgcn_mfma_f32_16x16x32_bf16(vf, pf0, O[dt][0], 0, 0, 0);
        O[dt][1] = __builtin_amdgcn_mfma_f32_16x16x32_bf16(vf, pf1, O[dt][1], 0, 0, 0);
      }
    }
    __builtin_amdgcn_s_setprio(0);

    if (it < SEQ / 64 - 1) {
      __syncthreads();
      *(short8*)&Ks[kb0][r0][0] = k0r;
      *(short8*)&Ks[kb1][r1][0] = k1r;
      *(short8*)&Vt[kb0][r0][0] = v0r;
      *(short8*)&Vt[kb1][r1][0] = v1r;
      if (it < SEQ / 64 - 2) {
        const int tn = t0 + 128;
        k0r = *(const short8*)(Kb + (size_t)(tn + r0) * HDIM + kb0 * 8);
        k1r = *(const short8*)(Kb + (size_t)(tn + r1) * HDIM + kb1 * 8);
        v0r = *(const short8*)(VbT + (size_t)r0 * SEQ + tn + kb0 * 8);
        v1r = *(const short8*)(VbT + (size_t)r1 * SEQ + tn + kb1 * 8);
      }
      __builtin_amdgcn_sched_barrier(0);
      asm volatile("s_waitcnt lgkmcnt(0)" ::: "memory");
      __builtin_amdgcn_s_barrier();
      __builtin_amdgcn_sched_barrier(0);
    }
  }

  // one final cross-quad l reduction per q-half (q = l15 in both layouts)
#pragma unroll
  for (int qh = 0; qh < 2; ++qh) {
    l_acc[qh] += __shfl_xor(l_acc[qh], 16);
    l_acc[qh] += __shfl_xor(l_acc[qh], 32);
  }
  const float inv0 = 1.f / l_acc[0];
  const float inv1 = 1.f / l_acc[1];

#pragma unroll
  for (int qh = 0; qh < 2; ++qh) {
    const float inv = qh ? inv1 : inv0;
    const size_t rowbase = ((size_t)(b * SEQ + qrw + qh * 16 + l15)) * EMBED + h * 64;
#pragma unroll
    for (int dt = 0; dt < 4; ++dt) {
      uint2 w;
      w.x = pk2(O[dt][qh][0] * inv, O[dt][qh][1] * inv);
      w.y = pk2(O[dt][qh][2] * inv, O[dt][qh][3] * inv);
      *(uint2*)(ao + rowbase + dt * 16 + (quad << 2)) = w;
    }
  }
}

// ---------------------------------------------------------------------------
// Output projection v5: A (ao, bf16) staged via global_load_lds as before;
// W = out_w f32 converted during staging (same T14 split as qkv). 128x128
// tile, grid 256, XCD-chunked map (A 1MB + W 2MB f32 per XCD ~ L2-resident).
// ---------------------------------------------------------------------------
__global__ __launch_bounds__(256, 2)
void proj_gemm(const u16* __restrict__ A, const float* __restrict__ W,
               const float* __restrict__ bias, float* __restrict__ out) {
  __shared__ u16 As[2][4][128][8];   // 8 KB per buf
  __shared__ u16 Bs[2][4][128][8];
  const int tid  = threadIdx.x;
  const int lane = tid & 63, wv = tid >> 6;
  const int l15  = lane & 15, quad = lane >> 4;
  const int wm = (wv >> 1) << 6, wn = (wv & 1) << 6;

  // block map: XCD(bid&7) -> 4 m-panels x all 8 n-panels
  const int bid = blockIdx.x;
  const int xcd = bid & 7, idx = bid >> 3;         // idx 0..31
  const int mb = (xcd << 2) | (idx & 3);           // 0..31
  const int nb = idx >> 2;                         // 0..7
  const int m0 = mb << 7, n0 = nb << 7;

  // staging slots: 512 per array, 2 per thread
  const int kb0 = tid >> 7, r0 = tid & 127;
  const int kb1 = kb0 + 2, r1 = r0;

  floatx4 acc[4][4];
#pragma unroll
  for (int i = 0; i < 4; ++i)
#pragma unroll
    for (int j = 0; j < 4; ++j) acc[i][j] = {0.f, 0.f, 0.f, 0.f};

  float4 wb0, wb1, wb2, wb3;

#define PRJ_A_STAGE(kt, buf)                                                         \
  do {                                                                               \
    const int k0_ = (kt) << 5;                                                       \
    async_cp16(A + (size_t)(m0 + r0) * EMBED + k0_ + kb0 * 8, &As[buf][kb0][r0][0]); \
    async_cp16(A + (size_t)(m0 + r1) * EMBED + k0_ + kb1 * 8, &As[buf][kb1][r1][0]); \
  } while (0)

#define PRJ_W_LOAD(kt)                                                         \
  do {                                                                         \
    const float* wp0 = W + (size_t)(n0 + r0) * EMBED + ((kt) << 5) + kb0 * 8;  \
    const float* wp1 = W + (size_t)(n0 + r1) * EMBED + ((kt) << 5) + kb1 * 8;  \
    wb0 = *(const float4*)wp0; wb1 = *(const float4*)(wp0 + 4);                \
    wb2 = *(const float4*)wp1; wb3 = *(const float4*)(wp1 + 4);                \
  } while (0)

#define PRJ_W_WRITE(buf)                                                       \
  do {                                                                         \
    cvt8(wb0, wb1, &Bs[buf][kb0][r0][0]);                                      \
    cvt8(wb2, wb3, &Bs[buf][kb1][r1][0]);                                      \
  } while (0)

  // prologue
  PRJ_A_STAGE(0, 0);
  PRJ_W_LOAD(0);
  PRJ_W_WRITE(0);
  __syncthreads();

  for (int t = 0; t < 32; ++t) {
    const int cur = t & 1;
    if (t < 31) {
      PRJ_A_STAGE(t + 1, cur ^ 1);   // async -> LDS, in flight under MFMA
      PRJ_W_LOAD(t + 1);             // f32 -> regs, in flight under MFMA
    }
    short8 af[4], bf[4];
#pragma unroll
    for (int f = 0; f < 4; ++f) {
      af[f] = *(const short8*)&As[cur][quad][wm + f * 16 + l15][0];
      bf[f] = *(const short8*)&Bs[cur][quad][wn + f * 16 + l15][0];
    }
    __builtin_amdgcn_s_setprio(1);
#pragma unroll
    for (int i = 0; i < 4; ++i)
#pragma unroll
      for (int j = 0; j < 4; ++j)
        acc[i][j] = __builtin_amdgcn_mfma_f32_16x16x32_bf16(bf[j], af[i], acc[i][j], 0, 0, 0);
    __builtin_amdgcn_s_setprio(0);
    __builtin_amdgcn_sched_barrier(0);
    if (t < 31) PRJ_W_WRITE(cur ^ 1);
    __syncthreads();
  }
#undef PRJ_A_STAGE
#undef PRJ_W_LOAD
#undef PRJ_W_WRITE

  // D: row = quad*4+r -> col (4 consecutive n); col = l15 -> m
#pragma unroll
  for (int i = 0; i < 4; ++i) {
    int m = m0 + wm + i * 16 + l15;
#pragma unroll
    for (int j = 0; j < 4; ++j) {
      int col0 = n0 + wn + j * 16 + (quad << 2);
      float4 bv = *(const float4*)(bias + col0);
      float4 o;
      o.x = acc[i][j][0] + bv.x;
      o.y = acc[i][j][1] + bv.y;
      o.z = acc[i][j][2] + bv.z;
      o.w = acc[i][j][3] + bv.w;
      *(float4*)(out + (size_t)m * EMBED + col0) = o;
    }
  }
}

extern "C" void kernel_launch(void* const* d_in, const int* in_sizes, int n_in,
                              void* d_out, int out_size, void* d_ws, size_t ws_size,
                              hipStream_t stream) {
  const float* x     = (const float*)d_in[0];
  const int*   mask  = (const int*)d_in[1];
  const float* qkv_w = (const float*)d_in[2];
  const float* out_w = (const float*)d_in[3];
  const float* out_b = (const float*)d_in[4];
  float* out = (float*)d_out;

  const size_t per = (size_t)NBH * SEQ * HDIM;      // 4,194,304 elems
  u16* q_ws  = (u16*)d_ws;
  u16* k_ws  = q_ws + per;
  u16* vT_ws = k_ws + per;                          // V^T [bh][d][s]
  u16* ao    = vT_ws + per;                         // 4096 x 1024

  // 3 launches (cvt_all eliminated — conversion fused into GEMM staging)
  qkv_gemm<<<dim3(24, 32), 256, 0, stream>>>(x, qkv_w, q_ws, k_ws, vT_ws);
  attn_kernel<<<dim3(NBH, SEQ / 128), 256, 0, stream>>>(q_ws, k_ws, vT_ws, mask, ao);
  proj_gemm<<<256, 256, 0, stream>>>(ao, out_w, out_b, out);
}

// Round 9
// 239.130 us; speedup vs baseline: 1.1801x; 1.1801x over previous
//
#include <hip/hip_runtime.h>
#include <hip/hip_bf16.h>

#define BATCH 2
#define SEQ   2048
#define EMBED 1024
#define HEADS 16
#define HDIM  64
#define NBH   (BATCH*HEADS)

typedef __attribute__((ext_vector_type(8))) short short8;
typedef __attribute__((ext_vector_type(4))) float floatx4;
typedef unsigned short u16;
typedef unsigned int   u32;

#define LOG2E 1.4426950408889634f

// async global->LDS, 16B per lane. LDS dest must be wave-uniform base + lane*16.
__device__ __forceinline__ void async_cp16(const void* g, void* l) {
  __builtin_amdgcn_global_load_lds((const __attribute__((address_space(1))) void*)g,
                                   (__attribute__((address_space(3))) void*)l,
                                   16, 0, 0);
}

__device__ __forceinline__ u16 f2b(float f) {  // f32 -> bf16 RNE
  union { float f; u32 u; } x; x.f = f;
  return (u16)((x.u + 0x7fffu + ((x.u >> 16) & 1u)) >> 16);
}
__device__ __forceinline__ u32 pk2(float a, float b) {  // packed bf16x2 (RNE)
  __hip_bfloat162 t = __float22bfloat162_rn(make_float2(a, b));
  return *reinterpret_cast<u32*>(&t);
}
// convert 8 f32 (two float4) -> 8 bf16, one ds_write_b128
__device__ __forceinline__ void cvt8(const float4& a, const float4& b, void* lds) {
  uint4 o;
  o.x = pk2(a.x, a.y); o.y = pk2(a.z, a.w);
  o.z = pk2(b.x, b.y); o.w = pk2(b.z, b.w);
  *(uint4*)lds = o;
}
__device__ __forceinline__ float fexp2(float x) {  // 2^x, single v_exp_f32
#if __has_builtin(__builtin_amdgcn_exp2f)
  return __builtin_amdgcn_exp2f(x);
#else
  return __expf(x * 0.6931471805599453f);
#endif
}

// ---------------------------------------------------------------------------
// f32 -> bf16 conversion of the WEIGHTS only (streamed operands must be
// pre-converted: R8 showed f32 W streaming costs 96 MB FETCH). X is
// converted inside qkv_gemm (its per-XCD slice is L2-resident in f32).
// 1,048,576 float4 elems = wqkv (786432) + wob (262144). Grid 4096.
// ---------------------------------------------------------------------------
__global__ __launch_bounds__(256)
void cvt_w(const float* __restrict__ wqkv, const float* __restrict__ wo,
           u16* __restrict__ wqkvb, u16* __restrict__ wob) {
  const size_t t = (size_t)blockIdx.x * 256 + threadIdx.x;   // float4 index
  const float* src; u16* dst; size_t off;
  if (t < 786432) { src = wqkv; dst = wqkvb; off = t; }
  else { src = wo; dst = wob; off = t - 786432; }
  float4 v = *(const float4*)(src + off * 4);
  ushort4 o;
  o.x = f2b(v.x); o.y = f2b(v.y); o.z = f2b(v.z); o.w = f2b(v.w);
  *(ushort4*)(dst + off * 4) = o;
}

// ---------------------------------------------------------------------------
// Fused QKV GEMM v6: R6-best structure (128^2, BK=32, 2-phase dbuf,
// 3 blocks/CU, grid 768 packs exactly, XCD-chunked swizzle) with X staged
// directly from f32 (reg float4 loads -> pk2 -> ds_write_b128, T14
// issue-early/write-late; X slice per XCD = 2 MB f32, L2-resident so
// re-reads are cheap — R8 confirmed X-side f32 adds only ~16 MB FETCH).
// W staged via global_load_lds from pre-converted bf16 (wqkvb).
// Removes xb round-trip (8 MB write + 8 MB read) and 2/3 of cvt.
// n-blocks 0..15 (Q/K): swapped operands -> [bh][s][d] packed stores.
// n-blocks 16..23 (V):  normal operands  -> V^T [bh][d][s] packed stores.
// ---------------------------------------------------------------------------
__global__ __launch_bounds__(256, 3)
void qkv_gemm(const float* __restrict__ X, const u16* __restrict__ Wb,
              u16* __restrict__ q_ws, u16* __restrict__ k_ws,
              u16* __restrict__ vT_ws) {
  __shared__ u16 As[2][4][128][8];   // 8 KB per buf: [buf][k-chunk][row][8]
  __shared__ u16 Bs[2][4][128][8];
  const int tid  = threadIdx.x;
  const int lane = tid & 63, wv = tid >> 6;
  const int l15  = lane & 15, quad = lane >> 4;
  const int wm = (wv >> 1) << 6, wn = (wv & 1) << 6;

  // XCD-chunked bijective swizzle: 768 blocks = 8 XCDs x 96 (4 m x 24 n)
  const int orig = blockIdx.y * 24 + blockIdx.x;
  const int swz  = (orig & 7) * 96 + (orig >> 3);
  const int m0 = (swz / 24) << 7, n0 = (swz % 24) << 7;
  const bool vpath = (n0 >= 2048);

  // staging slots: 512 per array of 8 bf16; 2 per thread
  const int kb0 = tid >> 7, r0 = tid & 127;        // {0,1}
  const int kb1 = kb0 + 2, r1 = r0;                // {2,3}

  floatx4 acc[4][4];
#pragma unroll
  for (int i = 0; i < 4; ++i)
#pragma unroll
    for (int j = 0; j < 4; ++j) acc[i][j] = {0.f, 0.f, 0.f, 0.f};

  float4 xa0, xa1, xa2, xa3;

#define QKV_X_LOAD(kt)                                                         \
  do {                                                                         \
    const float* xp0 = X + (size_t)(m0 + r0) * EMBED + ((kt) << 5) + kb0 * 8;  \
    const float* xp1 = X + (size_t)(m0 + r1) * EMBED + ((kt) << 5) + kb1 * 8;  \
    xa0 = *(const float4*)xp0; xa1 = *(const float4*)(xp0 + 4);                \
    xa2 = *(const float4*)xp1; xa3 = *(const float4*)(xp1 + 4);                \
  } while (0)

#define QKV_X_WRITE(buf)                                                       \
  do {                                                                         \
    cvt8(xa0, xa1, &As[buf][kb0][r0][0]);                                      \
    cvt8(xa2, xa3, &As[buf][kb1][r1][0]);                                      \
  } while (0)

#define QKV_W_STAGE(kt, buf)                                                          \
  do {                                                                                \
    const int k0_ = (kt) << 5;                                                        \
    async_cp16(Wb + (size_t)(n0 + r0) * EMBED + k0_ + kb0 * 8, &Bs[buf][kb0][r0][0]); \
    async_cp16(Wb + (size_t)(n0 + r1) * EMBED + k0_ + kb1 * 8, &Bs[buf][kb1][r1][0]); \
  } while (0)

  // prologue: tile 0
  QKV_W_STAGE(0, 0);
  QKV_X_LOAD(0);
  QKV_X_WRITE(0);
  __syncthreads();

  if (!vpath) {
    for (int t = 0; t < 32; ++t) {
      const int cur = t & 1;
      if (t < 31) {
        QKV_W_STAGE(t + 1, cur ^ 1);   // async -> LDS, in flight under MFMA
        QKV_X_LOAD(t + 1);             // f32 -> regs, in flight under MFMA
      }
      short8 af[4], bf[4];
#pragma unroll
      for (int f = 0; f < 4; ++f) {
        af[f] = *(const short8*)&As[cur][quad][wm + f * 16 + l15][0];
        bf[f] = *(const short8*)&Bs[cur][quad][wn + f * 16 + l15][0];
      }
      __builtin_amdgcn_s_setprio(1);
#pragma unroll
      for (int i = 0; i < 4; ++i)
#pragma unroll
        for (int j = 0; j < 4; ++j)
          acc[i][j] = __builtin_amdgcn_mfma_f32_16x16x32_bf16(bf[j], af[i], acc[i][j], 0, 0, 0);
      __builtin_amdgcn_s_setprio(0);
      __builtin_amdgcn_sched_barrier(0);       // keep converts below MFMAs
      if (t < 31) QKV_X_WRITE(cur ^ 1);        // write-late (reg dep = vm wait)
      __syncthreads();                         // drains W-async + X-writes
    }

    // D: row = quad*4+r -> weight col (d); col = l15 -> X row (s)
#pragma unroll
    for (int i = 0; i < 4; ++i) {
      int mg = m0 + wm + i * 16 + l15;
      int b = mg >> 11, s = mg & 2047;
#pragma unroll
      for (int j = 0; j < 4; ++j) {
        int col0 = n0 + wn + j * 16 + (quad << 2);
        int c = col0 >> 10, hd = col0 & 1023;
        int h = hd >> 6, d0 = hd & 63;
        u16* dst = c ? k_ws : q_ws;
        uint2 w;
        w.x = pk2(acc[i][j][0], acc[i][j][1]);
        w.y = pk2(acc[i][j][2], acc[i][j][3]);
        *(uint2*)(dst + (((size_t)(b * HEADS + h)) * SEQ + s) * HDIM + d0) = w;
      }
    }
  } else {
    for (int t = 0; t < 32; ++t) {
      const int cur = t & 1;
      if (t < 31) {
        QKV_W_STAGE(t + 1, cur ^ 1);
        QKV_X_LOAD(t + 1);
      }
      short8 af[4], bf[4];
#pragma unroll
      for (int f = 0; f < 4; ++f) {
        af[f] = *(const short8*)&As[cur][quad][wm + f * 16 + l15][0];
        bf[f] = *(const short8*)&Bs[cur][quad][wn + f * 16 + l15][0];
      }
      __builtin_amdgcn_s_setprio(1);
#pragma unroll
      for (int i = 0; i < 4; ++i)
#pragma unroll
        for (int j = 0; j < 4; ++j)
          acc[i][j] = __builtin_amdgcn_mfma_f32_16x16x32_bf16(af[i], bf[j], acc[i][j], 0, 0, 0);
      __builtin_amdgcn_s_setprio(0);
      __builtin_amdgcn_sched_barrier(0);
      if (t < 31) QKV_X_WRITE(cur ^ 1);
      __syncthreads();
    }

    // D: row = quad*4+r -> s (4 consecutive); col = l15 -> weight col (h,d)
#pragma unroll
    for (int i = 0; i < 4; ++i) {
      int mg0 = m0 + wm + i * 16 + (quad << 2);
      int b = mg0 >> 11, s0 = mg0 & 2047;
#pragma unroll
      for (int j = 0; j < 4; ++j) {
        int col = n0 + wn + j * 16 + l15;
        int hd = col & 1023;
        int h = hd >> 6, d = hd & 63;
        uint2 w;
        w.x = pk2(acc[i][j][0], acc[i][j][1]);
        w.y = pk2(acc[i][j][2], acc[i][j][3]);
        *(uint2*)(vT_ws + (((size_t)(b * HEADS + h)) * HDIM + d) * SEQ + s0) = w;
      }
    }
  }
#undef QKV_X_LOAD
#undef QKV_X_WRITE
#undef QKV_W_STAGE
}

// ---------------------------------------------------------------------------
// Flash attention v9: 32 q-rows per wave (K/V fragment amortization).
// (unchanged from R3/R5/R6 — verified, <63 µs)
// ---------------------------------------------------------------------------
__global__ __launch_bounds__(256, 2)
void attn_kernel(const u16* __restrict__ q_ws, const u16* __restrict__ k_ws,
                 const u16* __restrict__ vT_ws, const int* __restrict__ mask,
                 u16* __restrict__ ao) {
  __shared__ u16 Ks[8][64][8];     // 8 KB [d/8][t][8]
  __shared__ u16 Vt[8][64][8];     // 8 KB [t/8][d][8]
  __shared__ u16 Ps[4][32][68];    // 17 KB P^T [wave][q][t+pad4]
  __shared__ float mskf[SEQ];      // 8 KB whole-row mask shift table

  const int tid  = threadIdx.x;
  const int lane = tid & 63, wv = tid >> 6;
  const int l15  = lane & 15, quad = lane >> 4;
  const int bh = blockIdx.x;                 // x = bh -> XCD = bh%8 (L2 reuse)
  const int b  = bh >> 4, h = bh & 15;
  const int qrw = (blockIdx.y << 7) + (wv << 5);   // 32 q-rows per wave

  const u16* Qb  = q_ws  + (size_t)bh * SEQ * HDIM;
  const u16* Kb  = k_ws  + (size_t)bh * SEQ * HDIM;
  const u16* VbT = vT_ws + (size_t)bh * HDIM * SEQ;

  // per-thread staging coords (wave-uniform kb, lane-contig r)
  const int kb0 = tid >> 6, r0 = tid & 63;
  const int kb1 = (tid + 256) >> 6, r1 = tid & 63;

  // mask -> fixed-shift table, once per block
#pragma unroll
  for (int i = 0; i < 8; ++i) {
    int idx = (i << 8) + tid;
    mskf[idx] = mask[b * SEQ + idx] ? -12.0f : -1e30f;
  }

  // tile 0 -> LDS (async, linear dest)
  async_cp16(Kb + (size_t)r0 * HDIM + kb0 * 8, &Ks[kb0][r0][0]);
  async_cp16(Kb + (size_t)r1 * HDIM + kb1 * 8, &Ks[kb1][r1][0]);
  async_cp16(VbT + (size_t)r0 * SEQ + kb0 * 8, &Vt[kb0][r0][0]);
  async_cp16(VbT + (size_t)r1 * SEQ + kb1 * 8, &Vt[kb1][r1][0]);

  // Q B-frags, two q-halves: B[k=d=quad*8+j][n=q=qh*16+l15], pre-scaled 1/8
  short8 qf[2][2];
#pragma unroll
  for (int qh = 0; qh < 2; ++qh)
#pragma unroll
    for (int s = 0; s < 2; ++s) {
      short8 v = *(const short8*)(Qb + (size_t)(qrw + qh * 16 + l15) * HDIM + s * 32 + quad * 8);
#pragma unroll
      for (int e = 0; e < 8; ++e) {
        union { float f; u32 u; } x;
        x.u = ((u32)(u16)v[e]) << 16;
        x.f *= 0.125f;
        v[e] = (short)(x.u >> 16);
      }
      qf[qh][s] = v;
    }

  // tile 1 -> regs
  short8 k0r, k1r, v0r, v1r;
  k0r = *(const short8*)(Kb + (size_t)(64 + r0) * HDIM + kb0 * 8);
  k1r = *(const short8*)(Kb + (size_t)(64 + r1) * HDIM + kb1 * 8);
  v0r = *(const short8*)(VbT + (size_t)r0 * SEQ + 64 + kb0 * 8);
  v1r = *(const short8*)(VbT + (size_t)r1 * SEQ + 64 + kb1 * 8);

  float l_acc[2] = {0.f, 0.f};     // in-lane partial sums (scaled 2^-12)
  floatx4 O[4][2];
#pragma unroll
  for (int dt = 0; dt < 4; ++dt)
#pragma unroll
    for (int qh = 0; qh < 2; ++qh) O[dt][qh] = {0.f, 0.f, 0.f, 0.f};

  __syncthreads();                 // tile0 + mask table visible (one-time drain)

  for (int it = 0; it < SEQ / 64; ++it) {
    const int t0 = it << 6;

    // S^T = K·(Q/8)^T : D[t=nt*16+quad*4+r][q=qh*16+l15]; kf reused 2x
    floatx4 sc[4][2];
    __builtin_amdgcn_s_setprio(1);
#pragma unroll
    for (int nt = 0; nt < 4; ++nt) {
      sc[nt][0] = {0.f, 0.f, 0.f, 0.f};
      sc[nt][1] = {0.f, 0.f, 0.f, 0.f};
#pragma unroll
      for (int s = 0; s < 2; ++s) {
        short8 kf = *(const short8*)&Ks[s * 4 + quad][nt * 16 + l15][0];
        sc[nt][0] = __builtin_amdgcn_mfma_f32_16x16x32_bf16(kf, qf[0][s], sc[nt][0], 0, 0, 0);
        sc[nt][1] = __builtin_amdgcn_mfma_f32_16x16x32_bf16(kf, qf[1][s], sc[nt][1], 0, 0, 0);
      }
    }
    __builtin_amdgcn_s_setprio(0);

    // p = 2^(s*log2e + msk); in-lane l accumulation; packed bf16 P^T store
#pragma unroll
    for (int nt = 0; nt < 4; ++nt) {
      const float4 m4 = *(const float4*)&mskf[t0 + nt * 16 + (quad << 2)];
#pragma unroll
      for (int qh = 0; qh < 2; ++qh) {
        float pv[4];
#pragma unroll
        for (int r = 0; r < 4; ++r) {
          pv[r] = fexp2(fmaf(sc[nt][qh][r], LOG2E, (&m4.x)[r]));
          l_acc[qh] += pv[r];
        }
        uint2 w;
        w.x = pk2(pv[0], pv[1]); w.y = pk2(pv[2], pv[3]);
        *(uint2*)&Ps[wv][qh * 16 + l15][nt * 16 + (quad << 2)] = w;
      }
    }

    // O^T += V^T·P^T : A = Vt (m=d), B = Ps (n=q); vf reused 2x; wave-local
    __builtin_amdgcn_s_setprio(1);
#pragma unroll
    for (int tch = 0; tch < 2; ++tch) {
      short8 pf0 = *(const short8*)&Ps[wv][l15][tch * 32 + quad * 8];
      short8 pf1 = *(const short8*)&Ps[wv][16 + l15][tch * 32 + quad * 8];
#pragma unroll
      for (int dt = 0; dt < 4; ++dt) {
        short8 vf = *(const short8*)&Vt[tch * 4 + quad][dt * 16 + l15][0];
        O[dt][0] = __builtin_amdgcn_mfma_f32_16x16x32_bf16(vf, pf0, O[dt][0], 0, 0, 0);
        O[dt][1] = __builtin_amdgcn_mfma_f32_16x16x32_bf16(vf, pf1, O[dt][1], 0, 0, 0);
      }
    }
    __builtin_amdgcn_s_setprio(0);

    if (it < SEQ / 64 - 1) {
      __syncthreads();
      *(short8*)&Ks[kb0][r0][0] = k0r;
      *(short8*)&Ks[kb1][r1][0] = k1r;
      *(short8*)&Vt[kb0][r0][0] = v0r;
      *(short8*)&Vt[kb1][r1][0] = v1r;
      if (it < SEQ / 64 - 2) {
        const int tn = t0 + 128;
        k0r = *(const short8*)(Kb + (size_t)(tn + r0) * HDIM + kb0 * 8);
        k1r = *(const short8*)(Kb + (size_t)(tn + r1) * HDIM + kb1 * 8);
        v0r = *(const short8*)(VbT + (size_t)r0 * SEQ + tn + kb0 * 8);
        v1r = *(const short8*)(VbT + (size_t)r1 * SEQ + tn + kb1 * 8);
      }
      __builtin_amdgcn_sched_barrier(0);
      asm volatile("s_waitcnt lgkmcnt(0)" ::: "memory");
      __builtin_amdgcn_s_barrier();
      __builtin_amdgcn_sched_barrier(0);
    }
  }

  // one final cross-quad l reduction per q-half (q = l15 in both layouts)
#pragma unroll
  for (int qh = 0; qh < 2; ++qh) {
    l_acc[qh] += __shfl_xor(l_acc[qh], 16);
    l_acc[qh] += __shfl_xor(l_acc[qh], 32);
  }
  const float inv0 = 1.f / l_acc[0];
  const float inv1 = 1.f / l_acc[1];

#pragma unroll
  for (int qh = 0; qh < 2; ++qh) {
    const float inv = qh ? inv1 : inv0;
    const size_t rowbase = ((size_t)(b * SEQ + qrw + qh * 16 + l15)) * EMBED + h * 64;
#pragma unroll
    for (int dt = 0; dt < 4; ++dt) {
      uint2 w;
      w.x = pk2(O[dt][qh][0] * inv, O[dt][qh][1] * inv);
      w.y = pk2(O[dt][qh][2] * inv, O[dt][qh][3] * inv);
      *(uint2*)(ao + rowbase + dt * 16 + (quad << 2)) = w;
    }
  }
}

// ---------------------------------------------------------------------------
// Output projection v4 (R6-verified): 128x128 tile, grid 256 = 1/CU perfect
// packing, both operands bf16 via global_load_lds (A = ao, W = wob), 2-phase
// dbuf, XCD-chunked map (A 1MB + W 2MB per XCD, L2-resident).
// ---------------------------------------------------------------------------
__global__ __launch_bounds__(256, 2)
void proj_gemm(const u16* __restrict__ A, const u16* __restrict__ W,
               const float* __restrict__ bias, float* __restrict__ out) {
  __shared__ u16 As[2][4][128][8];   // 8 KB per buf
  __shared__ u16 Bs[2][4][128][8];
  const int tid  = threadIdx.x;
  const int lane = tid & 63, wv = tid >> 6;
  const int l15  = lane & 15, quad = lane >> 4;
  const int wm = (wv >> 1) << 6, wn = (wv & 1) << 6;

  // block map: XCD(bid&7) -> 4 m-panels x all 8 n-panels
  const int bid = blockIdx.x;
  const int xcd = bid & 7, idx = bid >> 3;         // idx 0..31
  const int mb = (xcd << 2) | (idx & 3);           // 0..31
  const int nb = idx >> 2;                         // 0..7
  const int m0 = mb << 7, n0 = nb << 7;

  // staging slots: 512 per array, 2 per thread
  const int kb0 = tid >> 7, r0 = tid & 127;
  const int kb1 = kb0 + 2, r1 = r0;

  floatx4 acc[4][4];
#pragma unroll
  for (int i = 0; i < 4; ++i)
#pragma unroll
    for (int j = 0; j < 4; ++j) acc[i][j] = {0.f, 0.f, 0.f, 0.f};

#define PRJ_STAGE(kt, buf)                                                        \
  do {                                                                            \
    const int k0_ = (kt) << 5;                                                    \
    async_cp16(A + (size_t)(m0 + r0) * EMBED + k0_ + kb0 * 8, &As[buf][kb0][r0][0]); \
    async_cp16(A + (size_t)(m0 + r1) * EMBED + k0_ + kb1 * 8, &As[buf][kb1][r1][0]); \
    async_cp16(W + (size_t)(n0 + r0) * EMBED + k0_ + kb0 * 8, &Bs[buf][kb0][r0][0]); \
    async_cp16(W + (size_t)(n0 + r1) * EMBED + k0_ + kb1 * 8, &Bs[buf][kb1][r1][0]); \
  } while (0)

  PRJ_STAGE(0, 0);
  __syncthreads();

  for (int t = 0; t < 32; ++t) {
    const int cur = t & 1;
    if (t < 31) PRJ_STAGE(t + 1, cur ^ 1);
    short8 af[4], bf[4];
#pragma unroll
    for (int f = 0; f < 4; ++f) {
      af[f] = *(const short8*)&As[cur][quad][wm + f * 16 + l15][0];
      bf[f] = *(const short8*)&Bs[cur][quad][wn + f * 16 + l15][0];
    }
    __builtin_amdgcn_s_setprio(1);
#pragma unroll
    for (int i = 0; i < 4; ++i)
#pragma unroll
      for (int j = 0; j < 4; ++j)
        acc[i][j] = __builtin_amdgcn_mfma_f32_16x16x32_bf16(bf[j], af[i], acc[i][j], 0, 0, 0);
    __builtin_amdgcn_s_setprio(0);
    __syncthreads();
  }
#undef PRJ_STAGE

  // D: row = quad*4+r -> col (4 consecutive n); col = l15 -> m
#pragma unroll
  for (int i = 0; i < 4; ++i) {
    int m = m0 + wm + i * 16 + l15;
#pragma unroll
    for (int j = 0; j < 4; ++j) {
      int col0 = n0 + wn + j * 16 + (quad << 2);
      float4 bv = *(const float4*)(bias + col0);
      float4 o;
      o.x = acc[i][j][0] + bv.x;
      o.y = acc[i][j][1] + bv.y;
      o.z = acc[i][j][2] + bv.z;
      o.w = acc[i][j][3] + bv.w;
      *(float4*)(out + (size_t)m * EMBED + col0) = o;
    }
  }
}

extern "C" void kernel_launch(void* const* d_in, const int* in_sizes, int n_in,
                              void* d_out, int out_size, void* d_ws, size_t ws_size,
                              hipStream_t stream) {
  const float* x     = (const float*)d_in[0];
  const int*   mask  = (const int*)d_in[1];
  const float* qkv_w = (const float*)d_in[2];
  const float* out_w = (const float*)d_in[3];
  const float* out_b = (const float*)d_in[4];
  float* out = (float*)d_out;

  const size_t per = (size_t)NBH * SEQ * HDIM;      // 4,194,304 elems
  u16* wqkvb = (u16*)d_ws;                          // 3,145,728
  u16* wob   = wqkvb + 3145728;                     // 1,048,576
  u16* q_ws  = wob + 1048576;
  u16* k_ws  = q_ws + per;
  u16* vT_ws = k_ws + per;                          // V^T [bh][d][s]
  u16* ao    = vT_ws + per;                         // 4096 x 1024

  cvt_w<<<4096, 256, 0, stream>>>(qkv_w, out_w, wqkvb, wob);
  qkv_gemm<<<dim3(24, 32), 256, 0, stream>>>(x, wqkvb, q_ws, k_ws, vT_ws);
  attn_kernel<<<dim3(NBH, SEQ / 128), 256, 0, stream>>>(q_ws, k_ws, vT_ws, mask, ao);
  proj_gemm<<<256, 256, 0, stream>>>(ao, wob, out_b, out);
}

// Round 11
// 221.287 us; speedup vs baseline: 1.2752x; 1.0806x over previous
//
#include <hip/hip_runtime.h>
#include <hip/hip_bf16.h>

#define BATCH 2
#define SEQ   2048
#define EMBED 1024
#define HEADS 16
#define HDIM  64
#define NBH   (BATCH*HEADS)

typedef __attribute__((ext_vector_type(8))) short short8;
typedef __attribute__((ext_vector_type(4))) float floatx4;
typedef unsigned short u16;
typedef unsigned int   u32;

#define LOG2E 1.4426950408889634f

// async global->LDS, 16B per lane. LDS dest must be wave-uniform base + lane*16.
__device__ __forceinline__ void async_cp16(const void* g, void* l) {
  __builtin_amdgcn_global_load_lds((const __attribute__((address_space(1))) void*)g,
                                   (__attribute__((address_space(3))) void*)l,
                                   16, 0, 0);
}

__device__ __forceinline__ u16 f2b(float f) {  // f32 -> bf16 RNE
  union { float f; u32 u; } x; x.f = f;
  return (u16)((x.u + 0x7fffu + ((x.u >> 16) & 1u)) >> 16);
}
__device__ __forceinline__ u32 pk2(float a, float b) {  // packed bf16x2
  __hip_bfloat162 t = __float22bfloat162_rn(make_float2(a, b));
  return *reinterpret_cast<u32*>(&t);
}
__device__ __forceinline__ float fexp2(float x) {  // 2^x, single v_exp_f32
#if __has_builtin(__builtin_amdgcn_exp2f)
  return __builtin_amdgcn_exp2f(x);
#else
  return __expf(x * 0.6931471805599453f);
#endif
}

// ---------------------------------------------------------------------------
// f32 -> bf16 conversion of x, qkv_w, out_w (region bounds block-aligned).
// (R8/R9 lessons: fusing conversion into GEMM staging regresses — streamed
// operands blow up FETCH in f32, and reg-staged conversion exposes load
// latency on the critical path. Pre-converting everything once is best.)
// ---------------------------------------------------------------------------
__global__ __launch_bounds__(256)
void cvt_all(const float* __restrict__ x, const float* __restrict__ wqkv,
             const float* __restrict__ wo,
             u16* __restrict__ xb, u16* __restrict__ wqkvb, u16* __restrict__ wob) {
  const size_t t = (size_t)blockIdx.x * 256 + threadIdx.x;   // float4 index
  const float* src; u16* dst; size_t off;
  if (t < 1048576) { src = x; dst = xb; off = t; }
  else if (t < 1048576 + 786432) { src = wqkv; dst = wqkvb; off = t - 1048576; }
  else { src = wo; dst = wob; off = t - (1048576 + 786432); }
  float4 v = *(const float4*)(src + off * 4);
  ushort4 o;
  o.x = f2b(v.x); o.y = f2b(v.y); o.z = f2b(v.z); o.w = f2b(v.w);
  *(ushort4*)(dst + off * 4) = o;
}

// ---------------------------------------------------------------------------
// Fused QKV GEMM v3 (R6-verified, 63 µs): depth-2 counted-vmcnt pipeline,
// 3 LDS buffers (48 KB -> 3 blocks/CU, grid 768 packs exactly), XCD-chunked
// bijective swizzle. Measured insensitive to depth/barriers/traffic —
// this is the best-known qkv for this decomposition.
// n-blocks 0..15 (Q/K): swapped operands -> [bh][s][d] packed stores.
// n-blocks 16..23 (V):  normal operands  -> V^T [bh][d][s] packed stores.
// ---------------------------------------------------------------------------
__global__ __launch_bounds__(256, 3)
void qkv_gemm(const u16* __restrict__ X, const u16* __restrict__ W,
              u16* __restrict__ q_ws, u16* __restrict__ k_ws,
              u16* __restrict__ vT_ws) {
  __shared__ u16 As[3][4][128][8];   // 24 KB: [buf][k-chunk][row][8]
  __shared__ u16 Bs[3][4][128][8];   // 24 KB
  const int tid  = threadIdx.x;
  const int lane = tid & 63, wv = tid >> 6;
  const int l15  = lane & 15, quad = lane >> 4;
  const int wm = (wv >> 1) << 6, wn = (wv & 1) << 6;

  // XCD-chunked bijective swizzle: 768 blocks = 8 XCDs x 96 (4 m x 24 n)
  const int orig = blockIdx.y * 24 + blockIdx.x;
  const int swz  = (orig & 7) * 96 + (orig >> 3);
  const int m0 = (swz / 24) << 7, n0 = (swz % 24) << 7;
  const bool vpath = (n0 >= 2048);

  // staging coords: 512 slots of 16 B per array, 2 per thread
  const int kb0 = tid >> 7, r0 = tid & 127;            // slot tid
  const int kb1 = (tid + 256) >> 7, r1 = tid & 127;    // slot tid+256

  floatx4 acc[4][4];
#pragma unroll
  for (int i = 0; i < 4; ++i)
#pragma unroll
    for (int j = 0; j < 4; ++j) acc[i][j] = {0.f, 0.f, 0.f, 0.f};

#define QKV_STAGE(kt, buf)                                                        \
  do {                                                                            \
    const int k0_ = (kt) << 5;                                                    \
    async_cp16(X + (size_t)(m0 + r0) * EMBED + k0_ + kb0 * 8, &As[buf][kb0][r0][0]); \
    async_cp16(X + (size_t)(m0 + r1) * EMBED + k0_ + kb1 * 8, &As[buf][kb1][r1][0]); \
    async_cp16(W + (size_t)(n0 + r0) * EMBED + k0_ + kb0 * 8, &Bs[buf][kb0][r0][0]); \
    async_cp16(W + (size_t)(n0 + r1) * EMBED + k0_ + kb1 * 8, &Bs[buf][kb1][r1][0]); \
  } while (0)

  // prologue: tiles 0,1 in flight
  QKV_STAGE(0, 0);
  QKV_STAGE(1, 1);

  if (!vpath) {
    for (int t = 0; t < 32; ++t) {
      const int cb = t % 3;
      if (t < 30) QKV_STAGE(t + 2, (t + 2) % 3);
      if (t < 30)      asm volatile("s_waitcnt vmcnt(8)" ::: "memory");
      else if (t == 30) asm volatile("s_waitcnt vmcnt(4)" ::: "memory");
      else              asm volatile("s_waitcnt vmcnt(0)" ::: "memory");
      __builtin_amdgcn_sched_barrier(0);
      __builtin_amdgcn_s_barrier();              // B1: tile t visible
      __builtin_amdgcn_sched_barrier(0);
      short8 af[4], bf[4];
#pragma unroll
      for (int f = 0; f < 4; ++f) {
        af[f] = *(const short8*)&As[cb][quad][wm + f * 16 + l15][0];
        bf[f] = *(const short8*)&Bs[cb][quad][wn + f * 16 + l15][0];
      }
      __builtin_amdgcn_s_setprio(1);
#pragma unroll
      for (int i = 0; i < 4; ++i)
#pragma unroll
        for (int j = 0; j < 4; ++j)
          acc[i][j] = __builtin_amdgcn_mfma_f32_16x16x32_bf16(bf[j], af[i], acc[i][j], 0, 0, 0);
      __builtin_amdgcn_s_setprio(0);
      asm volatile("s_waitcnt lgkmcnt(0)" ::: "memory");
      __builtin_amdgcn_sched_barrier(0);
      __builtin_amdgcn_s_barrier();              // B2: reads of buf done
      __builtin_amdgcn_sched_barrier(0);
    }

    // D: row = quad*4+r -> weight col (d); col = l15 -> X row (s)
#pragma unroll
    for (int i = 0; i < 4; ++i) {
      int mg = m0 + wm + i * 16 + l15;
      int b = mg >> 11, s = mg & 2047;
#pragma unroll
      for (int j = 0; j < 4; ++j) {
        int col0 = n0 + wn + j * 16 + (quad << 2);
        int c = col0 >> 10, hd = col0 & 1023;
        int h = hd >> 6, d0 = hd & 63;
        u16* dst = c ? k_ws : q_ws;
        uint2 w;
        w.x = pk2(acc[i][j][0], acc[i][j][1]);
        w.y = pk2(acc[i][j][2], acc[i][j][3]);
        *(uint2*)(dst + (((size_t)(b * HEADS + h)) * SEQ + s) * HDIM + d0) = w;
      }
    }
  } else {
    for (int t = 0; t < 32; ++t) {
      const int cb = t % 3;
      if (t < 30) QKV_STAGE(t + 2, (t + 2) % 3);
      if (t < 30)      asm volatile("s_waitcnt vmcnt(8)" ::: "memory");
      else if (t == 30) asm volatile("s_waitcnt vmcnt(4)" ::: "memory");
      else              asm volatile("s_waitcnt vmcnt(0)" ::: "memory");
      __builtin_amdgcn_sched_barrier(0);
      __builtin_amdgcn_s_barrier();
      __builtin_amdgcn_sched_barrier(0);
      short8 af[4], bf[4];
#pragma unroll
      for (int f = 0; f < 4; ++f) {
        af[f] = *(const short8*)&As[cb][quad][wm + f * 16 + l15][0];
        bf[f] = *(const short8*)&Bs[cb][quad][wn + f * 16 + l15][0];
      }
      __builtin_amdgcn_s_setprio(1);
#pragma unroll
      for (int i = 0; i < 4; ++i)
#pragma unroll
        for (int j = 0; j < 4; ++j)
          acc[i][j] = __builtin_amdgcn_mfma_f32_16x16x32_bf16(af[i], bf[j], acc[i][j], 0, 0, 0);
      __builtin_amdgcn_s_setprio(0);
      asm volatile("s_waitcnt lgkmcnt(0)" ::: "memory");
      __builtin_amdgcn_sched_barrier(0);
      __builtin_amdgcn_s_barrier();
      __builtin_amdgcn_sched_barrier(0);
    }

    // D: row = quad*4+r -> s (4 consecutive); col = l15 -> weight col (h,d)
#pragma unroll
    for (int i = 0; i < 4; ++i) {
      int mg0 = m0 + wm + i * 16 + (quad << 2);
      int b = mg0 >> 11, s0 = mg0 & 2047;
#pragma unroll
      for (int j = 0; j < 4; ++j) {
        int col = n0 + wn + j * 16 + l15;
        int hd = col & 1023;
        int h = hd >> 6, d = hd & 63;
        uint2 w;
        w.x = pk2(acc[i][j][0], acc[i][j][1]);
        w.y = pk2(acc[i][j][2], acc[i][j][3]);
        *(uint2*)(vT_ws + (((size_t)(b * HEADS + h)) * HDIM + d) * SEQ + s0) = w;
      }
    }
  }
#undef QKV_STAGE
}

// ---------------------------------------------------------------------------
// Flash attention v9 (R3/R5/R6-verified): 32 q-rows per wave (K/V fragment
// amortization), XCD = bh%8 L2 locality, reg-staged K/V prefetch, fixed-max
// softmax, setprio on MFMA clusters.
// ---------------------------------------------------------------------------
__global__ __launch_bounds__(256, 2)
void attn_kernel(const u16* __restrict__ q_ws, const u16* __restrict__ k_ws,
                 const u16* __restrict__ vT_ws, const int* __restrict__ mask,
                 u16* __restrict__ ao) {
  __shared__ u16 Ks[8][64][8];     // 8 KB [d/8][t][8]
  __shared__ u16 Vt[8][64][8];     // 8 KB [t/8][d][8]
  __shared__ u16 Ps[4][32][68];    // 17 KB P^T [wave][q][t+pad4]
  __shared__ float mskf[SEQ];      // 8 KB whole-row mask shift table

  const int tid  = threadIdx.x;
  const int lane = tid & 63, wv = tid >> 6;
  const int l15  = lane & 15, quad = lane >> 4;
  const int bh = blockIdx.x;                 // x = bh -> XCD = bh%8 (L2 reuse)
  const int b  = bh >> 4, h = bh & 15;
  const int qrw = (blockIdx.y << 7) + (wv << 5);   // 32 q-rows per wave

  const u16* Qb  = q_ws  + (size_t)bh * SEQ * HDIM;
  const u16* Kb  = k_ws  + (size_t)bh * SEQ * HDIM;
  const u16* VbT = vT_ws + (size_t)bh * HDIM * SEQ;

  // per-thread staging coords (wave-uniform kb, lane-contig r)
  const int kb0 = tid >> 6, r0 = tid & 63;
  const int kb1 = (tid + 256) >> 6, r1 = tid & 63;

  // mask -> fixed-shift table, once per block
#pragma unroll
  for (int i = 0; i < 8; ++i) {
    int idx = (i << 8) + tid;
    mskf[idx] = mask[b * SEQ + idx] ? -12.0f : -1e30f;
  }

  // tile 0 -> LDS (async, linear dest)
  async_cp16(Kb + (size_t)r0 * HDIM + kb0 * 8, &Ks[kb0][r0][0]);
  async_cp16(Kb + (size_t)r1 * HDIM + kb1 * 8, &Ks[kb1][r1][0]);
  async_cp16(VbT + (size_t)r0 * SEQ + kb0 * 8, &Vt[kb0][r0][0]);
  async_cp16(VbT + (size_t)r1 * SEQ + kb1 * 8, &Vt[kb1][r1][0]);

  // Q B-frags, two q-halves: B[k=d=quad*8+j][n=q=qh*16+l15], pre-scaled 1/8
  short8 qf[2][2];
#pragma unroll
  for (int qh = 0; qh < 2; ++qh)
#pragma unroll
    for (int s = 0; s < 2; ++s) {
      short8 v = *(const short8*)(Qb + (size_t)(qrw + qh * 16 + l15) * HDIM + s * 32 + quad * 8);
#pragma unroll
      for (int e = 0; e < 8; ++e) {
        union { float f; u32 u; } x;
        x.u = ((u32)(u16)v[e]) << 16;
        x.f *= 0.125f;
        v[e] = (short)(x.u >> 16);
      }
      qf[qh][s] = v;
    }

  // tile 1 -> regs
  short8 k0r, k1r, v0r, v1r;
  k0r = *(const short8*)(Kb + (size_t)(64 + r0) * HDIM + kb0 * 8);
  k1r = *(const short8*)(Kb + (size_t)(64 + r1) * HDIM + kb1 * 8);
  v0r = *(const short8*)(VbT + (size_t)r0 * SEQ + 64 + kb0 * 8);
  v1r = *(const short8*)(VbT + (size_t)r1 * SEQ + 64 + kb1 * 8);

  float l_acc[2] = {0.f, 0.f};     // in-lane partial sums (scaled 2^-12)
  floatx4 O[4][2];
#pragma unroll
  for (int dt = 0; dt < 4; ++dt)
#pragma unroll
    for (int qh = 0; qh < 2; ++qh) O[dt][qh] = {0.f, 0.f, 0.f, 0.f};

  __syncthreads();                 // tile0 + mask table visible (one-time drain)

  for (int it = 0; it < SEQ / 64; ++it) {
    const int t0 = it << 6;

    // S^T = K·(Q/8)^T : D[t=nt*16+quad*4+r][q=qh*16+l15]; kf reused 2x
    floatx4 sc[4][2];
    __builtin_amdgcn_s_setprio(1);
#pragma unroll
    for (int nt = 0; nt < 4; ++nt) {
      sc[nt][0] = {0.f, 0.f, 0.f, 0.f};
      sc[nt][1] = {0.f, 0.f, 0.f, 0.f};
#pragma unroll
      for (int s = 0; s < 2; ++s) {
        short8 kf = *(const short8*)&Ks[s * 4 + quad][nt * 16 + l15][0];
        sc[nt][0] = __builtin_amdgcn_mfma_f32_16x16x32_bf16(kf, qf[0][s], sc[nt][0], 0, 0, 0);
        sc[nt][1] = __builtin_amdgcn_mfma_f32_16x16x32_bf16(kf, qf[1][s], sc[nt][1], 0, 0, 0);
      }
    }
    __builtin_amdgcn_s_setprio(0);

    // p = 2^(s*log2e + msk); in-lane l accumulation; packed bf16 P^T store
#pragma unroll
    for (int nt = 0; nt < 4; ++nt) {
      const float4 m4 = *(const float4*)&mskf[t0 + nt * 16 + (quad << 2)];
#pragma unroll
      for (int qh = 0; qh < 2; ++qh) {
        float pv[4];
#pragma unroll
        for (int r = 0; r < 4; ++r) {
          pv[r] = fexp2(fmaf(sc[nt][qh][r], LOG2E, (&m4.x)[r]));
          l_acc[qh] += pv[r];
        }
        uint2 w;
        w.x = pk2(pv[0], pv[1]); w.y = pk2(pv[2], pv[3]);
        *(uint2*)&Ps[wv][qh * 16 + l15][nt * 16 + (quad << 2)] = w;
      }
    }

    // O^T += V^T·P^T : A = Vt (m=d), B = Ps (n=q); vf reused 2x; wave-local
    __builtin_amdgcn_s_setprio(1);
#pragma unroll
    for (int tch = 0; tch < 2; ++tch) {
      short8 pf0 = *(const short8*)&Ps[wv][l15][tch * 32 + quad * 8];
      short8 pf1 = *(const short8*)&Ps[wv][16 + l15][tch * 32 + quad * 8];
#pragma unroll
      for (int dt = 0; dt < 4; ++dt) {
        short8 vf = *(const short8*)&Vt[tch * 4 + quad][dt * 16 + l15][0];
        O[dt][0] = __builtin_amdgcn_mfma_f32_16x16x32_bf16(vf, pf0, O[dt][0], 0, 0, 0);
        O[dt][1] = __builtin_amdgcn_mfma_f32_16x16x32_bf16(vf, pf1, O[dt][1], 0, 0, 0);
      }
    }
    __builtin_amdgcn_s_setprio(0);

    if (it < SEQ / 64 - 1) {
      __syncthreads();
      *(short8*)&Ks[kb0][r0][0] = k0r;
      *(short8*)&Ks[kb1][r1][0] = k1r;
      *(short8*)&Vt[kb0][r0][0] = v0r;
      *(short8*)&Vt[kb1][r1][0] = v1r;
      if (it < SEQ / 64 - 2) {
        const int tn = t0 + 128;
        k0r = *(const short8*)(Kb + (size_t)(tn + r0) * HDIM + kb0 * 8);
        k1r = *(const short8*)(Kb + (size_t)(tn + r1) * HDIM + kb1 * 8);
        v0r = *(const short8*)(VbT + (size_t)r0 * SEQ + tn + kb0 * 8);
        v1r = *(const short8*)(VbT + (size_t)r1 * SEQ + tn + kb1 * 8);
      }
      __builtin_amdgcn_sched_barrier(0);
      asm volatile("s_waitcnt lgkmcnt(0)" ::: "memory");
      __builtin_amdgcn_s_barrier();
      __builtin_amdgcn_sched_barrier(0);
    }
  }

  // one final cross-quad l reduction per q-half (q = l15 in both layouts)
#pragma unroll
  for (int qh = 0; qh < 2; ++qh) {
    l_acc[qh] += __shfl_xor(l_acc[qh], 16);
    l_acc[qh] += __shfl_xor(l_acc[qh], 32);
  }
  const float inv0 = 1.f / l_acc[0];
  const float inv1 = 1.f / l_acc[1];

#pragma unroll
  for (int qh = 0; qh < 2; ++qh) {
    const float inv = qh ? inv1 : inv0;
    const size_t rowbase = ((size_t)(b * SEQ + qrw + qh * 16 + l15)) * EMBED + h * 64;
#pragma unroll
    for (int dt = 0; dt < 4; ++dt) {
      uint2 w;
      w.x = pk2(O[dt][qh][0] * inv, O[dt][qh][1] * inv);
      w.y = pk2(O[dt][qh][2] * inv, O[dt][qh][3] * inv);
      *(uint2*)(ao + rowbase + dt * 16 + (quad << 2)) = w;
    }
  }
}

// ---------------------------------------------------------------------------
// Output projection v3 (R6-verified): depth-2 counted-vmcnt pipeline, 3 bufs
// (36 KB, 2 blocks/CU), XCD swizzle (512 = 8x64). 128x64 tiles, swapped
// operands, float4 stores + bias.
// ---------------------------------------------------------------------------
__global__ __launch_bounds__(256, 2)
void proj_gemm(const u16* __restrict__ A, const u16* __restrict__ W,
               const float* __restrict__ bias, float* __restrict__ out) {
  __shared__ u16 As[3][4][128][8];   // 24 KB
  __shared__ u16 Bs[3][4][64][8];    // 12 KB
  const int tid  = threadIdx.x;
  const int lane = tid & 63, wv = tid >> 6;
  const int l15  = lane & 15, quad = lane >> 4;
  const int wm = (wv >> 1) << 6, wn = (wv & 1) << 5;

  // XCD-chunked bijective swizzle: 512 blocks = 8 XCDs x 64 (4 m x 16 n)
  const int orig = blockIdx.y * 16 + blockIdx.x;
  const int swz  = (orig & 7) * 64 + (orig >> 3);
  const int m0 = (swz / 16) << 7, n0 = (swz % 16) << 6;

  // staging coords: A has 512 slots (2/thread), B has 256 slots (1/thread)
  const int kbA0 = tid >> 7, rA0 = tid & 127;
  const int kbA1 = (tid + 256) >> 7, rA1 = tid & 127;
  const int kbB  = tid >> 6, rB = tid & 63;

  floatx4 acc[4][2];
#pragma unroll
  for (int i = 0; i < 4; ++i)
#pragma unroll
    for (int j = 0; j < 2; ++j) acc[i][j] = {0.f, 0.f, 0.f, 0.f};

#define PRJ_STAGE(kt, buf)                                                           \
  do {                                                                               \
    const int k0_ = (kt) << 5;                                                       \
    async_cp16(A + (size_t)(m0 + rA0) * EMBED + k0_ + kbA0 * 8, &As[buf][kbA0][rA0][0]); \
    async_cp16(A + (size_t)(m0 + rA1) * EMBED + k0_ + kbA1 * 8, &As[buf][kbA1][rA1][0]); \
    async_cp16(W + (size_t)(n0 + rB) * EMBED + k0_ + kbB * 8, &Bs[buf][kbB][rB][0]);     \
  } while (0)

  PRJ_STAGE(0, 0);
  PRJ_STAGE(1, 1);

  for (int t = 0; t < 32; ++t) {
    const int cb = t % 3;
    if (t < 30) PRJ_STAGE(t + 2, (t + 2) % 3);
    if (t < 30)      asm volatile("s_waitcnt vmcnt(6)" ::: "memory");
    else if (t == 30) asm volatile("s_waitcnt vmcnt(3)" ::: "memory");
    else              asm volatile("s_waitcnt vmcnt(0)" ::: "memory");
    __builtin_amdgcn_sched_barrier(0);
    __builtin_amdgcn_s_barrier();              // B1: tile t visible
    __builtin_amdgcn_sched_barrier(0);
    short8 af[4], bf[2];
#pragma unroll
    for (int f = 0; f < 4; ++f)
      af[f] = *(const short8*)&As[cb][quad][wm + f * 16 + l15][0];
#pragma unroll
    for (int f = 0; f < 2; ++f)
      bf[f] = *(const short8*)&Bs[cb][quad][wn + f * 16 + l15][0];
    __builtin_amdgcn_s_setprio(1);
#pragma unroll
    for (int i = 0; i < 4; ++i)
#pragma unroll
      for (int j = 0; j < 2; ++j)
        acc[i][j] = __builtin_amdgcn_mfma_f32_16x16x32_bf16(bf[j], af[i], acc[i][j], 0, 0, 0);
    __builtin_amdgcn_s_setprio(0);
    asm volatile("s_waitcnt lgkmcnt(0)" ::: "memory");
    __builtin_amdgcn_sched_barrier(0);
    __builtin_amdgcn_s_barrier();              // B2: reads done
    __builtin_amdgcn_sched_barrier(0);
  }
#undef PRJ_STAGE

  // D: row = quad*4+r -> col (4 consecutive n); col = l15 -> m
#pragma unroll
  for (int i = 0; i < 4; ++i) {
    int m = m0 + wm + i * 16 + l15;
#pragma unroll
    for (int j = 0; j < 2; ++j) {
      int col0 = n0 + wn + j * 16 + (quad << 2);
      float4 bv = *(const float4*)(bias + col0);
      float4 o;
      o.x = acc[i][j][0] + bv.x;
      o.y = acc[i][j][1] + bv.y;
      o.z = acc[i][j][2] + bv.z;
      o.w = acc[i][j][3] + bv.w;
      *(float4*)(out + (size_t)m * EMBED + col0) = o;
    }
  }
}

extern "C" void kernel_launch(void* const* d_in, const int* in_sizes, int n_in,
                              void* d_out, int out_size, void* d_ws, size_t ws_size,
                              hipStream_t stream) {
  const float* x     = (const float*)d_in[0];
  const int*   mask  = (const int*)d_in[1];
  const float* qkv_w = (const float*)d_in[2];
  const float* out_w = (const float*)d_in[3];
  const float* out_b = (const float*)d_in[4];
  float* out = (float*)d_out;

  const size_t per = (size_t)NBH * SEQ * HDIM;      // 4,194,304 elems
  u16* xb    = (u16*)d_ws;                          // 4,194,304
  u16* wqkvb = xb + 4194304;                        // 3,145,728
  u16* wob   = wqkvb + 3145728;                     // 1,048,576
  u16* q_ws  = wob + 1048576;
  u16* k_ws  = q_ws + per;
  u16* vT_ws = k_ws + per;                          // V^T [bh][d][s]
  u16* ao    = vT_ws + per;                         // 4096 x 1024

  cvt_all<<<8192, 256, 0, stream>>>(x, qkv_w, out_w, xb, wqkvb, wob);
  qkv_gemm<<<dim3(24, 32), 256, 0, stream>>>(xb, wqkvb, q_ws, k_ws, vT_ws);
  // x = bh (XCD = bh%8, L2-resident K/V); y = q-chunk of 128 rows
  attn_kernel<<<dim3(NBH, SEQ / 128), 256, 0, stream>>>(q_ws, k_ws, vT_ws, mask, ao);
  proj_gemm<<<dim3(16, 32), 256, 0, stream>>>(ao, wob, out_b, out);
}